// Round 8
// baseline (237.444 us; speedup 1.0000x reference)
//
#include <hip/hip_runtime.h>

// ---------------- constants ----------------
#define BATCH   131072
#define INDIM   1024
#define BM      64
#define BDIM    256
#define NBLK    (BATCH / BM)          // 2048

// ---- LDS layout (bytes), phase-multiplexed ----
#define WT0_OFF  0                    // G1 w-tile buf0 [384][32] bf16 (24576), wave-private strips
#define WT1_OFF  24576                // buf1 -> 49152
#define XTA_OFF  49152                // x-tile pair A: 2x[64][32] (8192) -> 57344
#define XTB_OFF  57344                // pair B -> 65536
#define Z1_OFF   0                    // z1 [64][392] bf16 (50176)
#define W2T0_OFF 50176                // w2 tile buf0 [128][32] (8192)
#define W2T1_OFF 58368                // buf1 -> 66560
#define FZ_OFF   0                    // fused [64][264] bf16 (33792)
#define RP_OFF   33792                // rowpart [64][4] f32 (1024)
#define W3T_OFF  42240                // w3 tile [384][32] (24576) -> 66816
#define CB_OFF   66816
#define B1S_OFF  (CB_OFF)             // 384 f32
#define B2S_OFF  (CB_OFF + 1536)      // 128 f32
#define B3S_OFF  (CB_OFF + 2048)      // 384 f32
#define W4S_OFF  (CB_OFF + 3584)      // 384 f32
#define MKS_OFF  (CB_OFF + 5120)      // mk bf16 [32][136] (8704)
#define SMEM_BYTES (CB_OFF + 13824)   // 80640 -> 2 blocks/CU

typedef unsigned short u16;
typedef u16    u16x8  __attribute__((ext_vector_type(8)));
typedef u16    u16x4  __attribute__((ext_vector_type(4)));
typedef __bf16 bf16x8 __attribute__((ext_vector_type(8)));
typedef __bf16 bf16x4 __attribute__((ext_vector_type(4)));
typedef float  f32x4  __attribute__((ext_vector_type(4)));

__device__ __forceinline__ u16 f2bf(float f) {
  unsigned u = __float_as_uint(f);
  u += 0x7FFFu + ((u >> 16) & 1u);    // RNE
  return (u16)(u >> 16);
}

// tanh-form GELU via sigmoid (max abs err ~3e-4, budget 1e-2)
__device__ __forceinline__ float gelu_fast(float v) {
  float t = v * v;
  float u = v * fmaf(t, 0.0356774081f, 0.7978845608f);
  float e = __builtin_amdgcn_exp2f(u * -2.885390082f);
  return v * __builtin_amdgcn_rcpf(1.0f + e);
}

__device__ __forceinline__ f32x4 mfma16(u16x8 a, u16x8 b, f32x4 c) {
  return __builtin_amdgcn_mfma_f32_16x16x32_bf16(
      __builtin_bit_cast(bf16x8, a), __builtin_bit_cast(bf16x8, b), c, 0, 0, 0);
}

__device__ __forceinline__ u16x8 cvt8(float4 a, float4 b) {
  bf16x8 r;
  r[0]=(__bf16)a.x; r[1]=(__bf16)a.y; r[2]=(__bf16)a.z; r[3]=(__bf16)a.w;
  r[4]=(__bf16)b.x; r[5]=(__bf16)b.y; r[6]=(__bf16)b.z; r[7]=(__bf16)b.w;
  return __builtin_bit_cast(u16x8, r);
}
__device__ __forceinline__ u16x4 cvt4(float4 a) {
  bf16x4 r;
  r[0]=(__bf16)a.x; r[1]=(__bf16)a.y; r[2]=(__bf16)a.z; r[3]=(__bf16)a.w;
  return __builtin_bit_cast(u16x4, r);
}

typedef __attribute__((address_space(3))) unsigned int       lds_u32;
typedef __attribute__((address_space(1))) const unsigned int glb_u32;
__device__ __forceinline__ void gload16(const void* g, void* l) {
  __builtin_amdgcn_global_load_lds((glb_u32*)g, (lds_u32*)l, 16, 0, 0);
}

#define FENCE_SCHED __builtin_amdgcn_sched_barrier(0)
#define WAIT_LGKM0 do { asm volatile("s_waitcnt lgkmcnt(0)" ::: "memory"); FENCE_SCHED; } while (0)
#define WAIT_VMN(N) do { asm volatile("s_waitcnt vmcnt(" #N ")" ::: "memory"); FENCE_SCHED; } while (0)
// barrier with lgkm-only drain: DMA prefetches stay in flight across phases
#define BARRIER_LGKM do { \
  asm volatile("s_waitcnt lgkmcnt(0)" ::: "memory"); \
  __builtin_amdgcn_s_barrier(); FENCE_SCHED; } while (0)

// ---------------- prep: bf16-cast + transpose into chunk-swizzled K-tiles ----------------
// all tiles [N][32], 16B chunk cp holds source k-chunk cp^((r>>1)&3)
__global__ void prep_kernel(const float* __restrict__ w1, const float* __restrict__ w2,
                            const float* __restrict__ w3, u16* __restrict__ w1s,
                            u16* __restrict__ w2s, u16* __restrict__ w3s) {
  int i = blockIdx.x * 256 + threadIdx.x;
  if (i < 393216) {                       // 32 tiles [384][32]
    int t = i / 12288, p = i % 12288;
    int r = p >> 5, q = p & 31, cp = q >> 3, o = q & 7;
    int k = t * 32 + ((cp ^ ((r >> 1) & 3)) << 3) + o;
    w1s[i] = f2bf(w1[k * 384 + r]);
  } else if (i < 442368) {                // 12 tiles [128][32]
    int j = i - 393216;
    int t = j / 4096, p = j % 4096;
    int r = p >> 5, q = p & 31, cp = q >> 3, o = q & 7;
    int k = t * 32 + ((cp ^ ((r >> 1) & 3)) << 3) + o;
    w2s[j] = f2bf(w2[k * 128 + r]);
  } else if (i < 540672) {                // 8 tiles [384][32]
    int j = i - 442368;
    int t = j / 12288, p = j % 12288;
    int r = p >> 5, q = p & 31, cp = q >> 3, o = q & 7;
    int k = t * 32 + ((cp ^ ((r >> 1) & 3)) << 3) + o;
    w3s[j] = f2bf(w3[k * 384 + r]);
  }
}

// ---------------- fused forward: 4 waves, wave tile 64x96 ----------------
__global__ __launch_bounds__(BDIM, 2) void fused_kernel(
    const float* __restrict__ x,  const u16* __restrict__ w1s,
    const float* __restrict__ b1, const u16* __restrict__ w2s,
    const float* __restrict__ b2, const float* __restrict__ mkw,
    const float* __restrict__ mvw, const u16* __restrict__ w3s,
    const float* __restrict__ b3, const float* __restrict__ w4,
    const float* __restrict__ b4, float* __restrict__ out) {
  extern __shared__ char smem[];
  u16*   z1  = (u16*)(smem + Z1_OFF);
  u16*   fz  = (u16*)(smem + FZ_OFF);
  u16*   w3t = (u16*)(smem + W3T_OFF);
  u16*   wt0 = (u16*)(smem + WT0_OFF);
  u16*   wt1 = (u16*)(smem + WT1_OFF);
  u16*   w2t0 = (u16*)(smem + W2T0_OFF);
  u16*   w2t1 = (u16*)(smem + W2T1_OFF);
  float* b1s = (float*)(smem + B1S_OFF);
  float* b2s = (float*)(smem + B2S_OFF);
  float* b3s = (float*)(smem + B3S_OFF);
  float* w4s = (float*)(smem + W4S_OFF);
  u16*   mks = (u16*)(smem + MKS_OFF);
  float* rowpart = (float*)(smem + RP_OFF);

  const int tid  = threadIdx.x;
  const int lane = tid & 63;
  const int wid  = tid >> 6;          // 0..3: wave owns 96 w-cols (G1/G3), 32 (G2)
  const int l15  = lane & 15;
  const int g    = lane >> 4;         // 0..3
  const int sw8  = (g ^ ((l15 >> 1) & 3)) * 8;   // swizzled chunk (u16 offset)
  const int row0 = blockIdx.x * BM;
  const int wrow = wid * 96;
  const int wstrip = wid * 3072;      // 96-row strip in [384][32] (u16)

  // ---------- prologue ----------
  // W strips for kt=0 (->WT0) and kt=1 (->WT1): 6 gloads each
  {
    const u16* ws = w1s + wstrip + lane * 8;
    #pragma unroll
    for (int i = 0; i < 6; ++i) gload16(ws + i * 512, wt0 + wstrip + i * 512);
    const u16* ws1 = ws + 12288;
    #pragma unroll
    for (int i = 0; i < 6; ++i) gload16(ws1 + i * 512, wt1 + wstrip + i * 512);
  }
  FENCE_SCHED;
  // x: thread covers row=tid>>2, 8 k-cols (tid&3)*8; one u16x8 publish per tile
  const int xrow = tid >> 2, xq = tid & 3;
  const float* xp = x + (long)(row0 + xrow) * INDIM + xq * 8;
  const int xpub = xrow * 32 + ((xq ^ ((xrow >> 1) & 3)) << 3);
  float4 xA0 = *(const float4*)xp,        xA1 = *(const float4*)(xp + 4);
  float4 xB0 = *(const float4*)(xp + 32), xB1 = *(const float4*)(xp + 36);

  for (int i = tid; i < 384; i += BDIM) b1s[i] = b1[i];
  if (tid < 128) b2s[tid] = b2[tid];
  for (int i = tid; i < 384; i += BDIM) b3s[i] = b3[i];
  for (int i = tid; i < 384; i += BDIM) w4s[i] = w4[i];
  {
    int r = tid >> 3, cc = (tid & 7) * 16;
    const float4* pm = (const float4*)(mkw + r * 128 + cc);
    *(u16x8*)(mks + r * 136 + cc)     = cvt8(pm[0], pm[1]);
    *(u16x8*)(mks + r * 136 + cc + 8) = cvt8(pm[2], pm[3]);
  }
  // publish xt[0], xt[1] into pair A (implicit wait drains prologue loads; prologue-only)
  *(u16x8*)((u16*)(smem + XTA_OFF) + xpub)        = cvt8(xA0, xA1);
  *(u16x8*)((u16*)(smem + XTA_OFF) + 2048 + xpub) = cvt8(xB0, xB1);
  // stream x(2), x(3)
  xA0 = *(const float4*)(xp + 64); xA1 = *(const float4*)(xp + 68);
  xB0 = *(const float4*)(xp + 96); xB1 = *(const float4*)(xp + 100);
  BARRIER_LGKM;   // in-flight: W0:6, W1:6, x:4

  // =========== GEMM1: z1 = gelu(x@w1+b1) [64x384], K=1024, BK=32, 2 kt/phase ===========
  f32x4 acc[4][6];
  #pragma unroll
  for (int m = 0; m < 4; ++m)
    #pragma unroll
    for (int n = 0; n < 6; ++n) acc[m][n] = (f32x4){0.f, 0.f, 0.f, 0.f};

  for (int p = 0; p < 15; ++p) {
    const u16* xrb = (const u16*)(smem + ((p & 1) ? XTB_OFF : XTA_OFF));
    u16* xwb = (u16*)(smem + ((p & 1) ? XTA_OFF : XTB_OFF));
    // ---- kt = 2p (WT0) ----
    WAIT_VMN(10);                    // W(2p) landed; [W(2p+1):6, x:4] fly
    {
      u16x8 af[4], bfr[6];
      #pragma unroll
      for (int m = 0; m < 4; ++m) af[m] = *(const u16x8*)(xrb + (m * 16 + l15) * 32 + sw8);
      #pragma unroll
      for (int n = 0; n < 6; ++n) bfr[n] = *(const u16x8*)(wt0 + (wrow + n * 16 + l15) * 32 + sw8);
      WAIT_LGKM0;                    // my WT0 strip reads done -> overwrite OK
      const u16* ws = w1s + (2 * p + 2) * 12288 + wstrip + lane * 8;
      #pragma unroll
      for (int i = 0; i < 6; ++i) gload16(ws + i * 512, wt0 + wstrip + i * 512);
      #pragma unroll
      for (int m = 0; m < 4; ++m)
        #pragma unroll
        for (int n = 0; n < 6; ++n) acc[m][n] = mfma16(bfr[n], af[m], acc[m][n]);
    }
    // ---- kt = 2p+1 (WT1) ----
    WAIT_VMN(10);                    // W(2p+1) landed; [x:4, W(2p+2):6] fly
    {
      u16x8 af[4], bfr[6];
      #pragma unroll
      for (int m = 0; m < 4; ++m) af[m] = *(const u16x8*)(xrb + 2048 + (m * 16 + l15) * 32 + sw8);
      #pragma unroll
      for (int n = 0; n < 6; ++n) bfr[n] = *(const u16x8*)(wt1 + (wrow + n * 16 + l15) * 32 + sw8);
      WAIT_LGKM0;
      const u16* ws = w1s + (2 * p + 3) * 12288 + wstrip + lane * 8;
      #pragma unroll
      for (int i = 0; i < 6; ++i) gload16(ws + i * 512, wt1 + wstrip + i * 512);
      #pragma unroll
      for (int m = 0; m < 4; ++m)
        #pragma unroll
        for (int n = 0; n < 6; ++n) acc[m][n] = mfma16(bfr[n], af[m], acc[m][n]);
    }
    // ---- publish xt(2p+2), xt(2p+3); implicit vmcnt(12) drains only the 4 x-loads ----
    *(u16x8*)(xwb + xpub)        = cvt8(xA0, xA1);
    *(u16x8*)(xwb + 2048 + xpub) = cvt8(xB0, xB1);
    if (p < 14) {                    // stream x(2p+4), x(2p+5)
      xA0 = *(const float4*)(xp + (2 * p + 4) * 32); xA1 = *(const float4*)(xp + (2 * p + 4) * 32 + 4);
      xB0 = *(const float4*)(xp + (2 * p + 5) * 32); xB1 = *(const float4*)(xp + (2 * p + 5) * 32 + 4);
    }
    BARRIER_LGKM;                    // steady in-flight: [W_e:6, W_o:6, x:4]
  }
  {   // ---- drain phase (kt 30,31) ----
    const u16* xrb = (const u16*)(smem + XTB_OFF);
    WAIT_VMN(6);                     // W30 landed
    {
      u16x8 af[4], bfr[6];
      #pragma unroll
      for (int m = 0; m < 4; ++m) af[m] = *(const u16x8*)(xrb + (m * 16 + l15) * 32 + sw8);
      #pragma unroll
      for (int n = 0; n < 6; ++n) bfr[n] = *(const u16x8*)(wt0 + (wrow + n * 16 + l15) * 32 + sw8);
      WAIT_LGKM0;
      #pragma unroll
      for (int m = 0; m < 4; ++m)
        #pragma unroll
        for (int n = 0; n < 6; ++n) acc[m][n] = mfma16(bfr[n], af[m], acc[m][n]);
    }
    WAIT_VMN(0);                     // W31 landed
    {
      u16x8 af[4], bfr[6];
      #pragma unroll
      for (int m = 0; m < 4; ++m) af[m] = *(const u16x8*)(xrb + 2048 + (m * 16 + l15) * 32 + sw8);
      #pragma unroll
      for (int n = 0; n < 6; ++n) bfr[n] = *(const u16x8*)(wt1 + (wrow + n * 16 + l15) * 32 + sw8);
      WAIT_LGKM0;
      #pragma unroll
      for (int m = 0; m < 4; ++m)
        #pragma unroll
        for (int n = 0; n < 6; ++n) acc[m][n] = mfma16(bfr[n], af[m], acc[m][n]);
    }
  }
  BARRIER_LGKM;                      // all staging reads done -> region reusable

  // G2 tiles 0,1 DMA (wave-private strips, land under z1 epilogue)
  {
    const u16* s2 = w2s + wid * 1024 + lane * 8;
    gload16(s2, w2t0 + wid * 1024); gload16(s2 + 512, w2t0 + wid * 1024 + 512);
    const u16* s2b = w2s + 4096 + wid * 1024 + lane * 8;
    gload16(s2b, w2t1 + wid * 1024); gload16(s2b + 512, w2t1 + wid * 1024 + 512);
  }
  // z1 epilogue: b64 writes of 4 consecutive cols
  #pragma unroll
  for (int m = 0; m < 4; ++m) {
    #pragma unroll
    for (int n = 0; n < 6; ++n) {
      int col = wrow + n * 16 + g * 4;
      float4 bv = *(const float4*)(b1s + col);
      f32x4 a = acc[m][n];
      float4 gv = {gelu_fast(a[0] + bv.x), gelu_fast(a[1] + bv.y),
                   gelu_fast(a[2] + bv.z), gelu_fast(a[3] + bv.w)};
      *(u16x4*)(z1 + (m * 16 + l15) * 392 + col) = cvt4(gv);
    }
  }
  BARRIER_LGKM;                      // z1 visible

  // =========== GEMM2: z = gelu(z1@w2+b2) [64x128], K=384, BK=32, no barriers ===========
  f32x4 acc2[4][2];
  #pragma unroll
  for (int m = 0; m < 4; ++m) { acc2[m][0] = (f32x4){0,0,0,0}; acc2[m][1] = (f32x4){0,0,0,0}; }
  for (int kt = 0; kt < 12; ++kt) {
    if (kt < 11) { WAIT_VMN(2); } else { WAIT_VMN(0); }
    const u16* wb = (kt & 1) ? w2t1 : w2t0;
    u16x8 a2f[4], b2f[2];
    #pragma unroll
    for (int m = 0; m < 4; ++m)
      a2f[m] = *(const u16x8*)(z1 + (m * 16 + l15) * 392 + kt * 32 + g * 8);
    #pragma unroll
    for (int n = 0; n < 2; ++n)
      b2f[n] = *(const u16x8*)(wb + (wid * 32 + n * 16 + l15) * 32 + sw8);
    WAIT_LGKM0;
    if (kt < 10) {
      const u16* s2 = w2s + (kt + 2) * 4096 + wid * 1024 + lane * 8;
      u16* d2 = ((kt & 1) ? w2t1 : w2t0) + wid * 1024;
      gload16(s2, d2); gload16(s2 + 512, d2 + 512);
    }
    #pragma unroll
    for (int m = 0; m < 4; ++m)
      #pragma unroll
      for (int n = 0; n < 2; ++n) acc2[m][n] = mfma16(b2f[n], a2f[m], acc2[m][n]);
  }
  BARRIER_LGKM;                      // z1/w2t dead -> fz & w3t regions usable

  // G3 tile-0 DMA early (covered by fz epilogue + logits + top2)
  {
    const u16* s3 = w3s + wstrip + lane * 8;
    #pragma unroll
    for (int i = 0; i < 6; ++i) gload16(s3 + i * 512, w3t + wstrip + i * 512);
  }
  // fz epilogue (z part)
  #pragma unroll
  for (int m = 0; m < 4; ++m) {
    #pragma unroll
    for (int n = 0; n < 2; ++n) {
      int col = wid * 32 + n * 16 + g * 4;
      float4 bv = *(const float4*)(b2s + col);
      f32x4 a = acc2[m][n];
      float4 gv = {gelu_fast(a[0] + bv.x), gelu_fast(a[1] + bv.y),
                   gelu_fast(a[2] + bv.z), gelu_fast(a[3] + bv.w)};
      *(u16x4*)(fz + (m * 16 + l15) * 264 + col) = cvt4(gv);
    }
  }
  BARRIER_LGKM;                      // fz(z) visible

  // =========== logits + in-register top-2 + mem blend (rows wid*16+l15) ===========
  {
    const int wr = wid * 16 + l15;
    f32x4 accl[2] = {(f32x4){0,0,0,0}, (f32x4){0,0,0,0}};
    #pragma unroll
    for (int ks = 0; ks < 4; ++ks) {
      u16x8 afz = *(const u16x8*)(fz + wr * 264 + ks * 32 + g * 8);
      u16x8 k0  = *(const u16x8*)(mks + l15 * 136 + ks * 32 + g * 8);
      u16x8 k1  = *(const u16x8*)(mks + (16 + l15) * 136 + ks * 32 + g * 8);
      accl[0] = mfma16(k0, afz, accl[0]);
      accl[1] = mfma16(k1, afz, accl[1]);
    }
    float m1 = -3.4e38f, m2 = -3.4e38f; int i1 = -1, i2 = -1;
    #pragma unroll
    for (int n = 0; n < 2; ++n)
      #pragma unroll
      for (int j = 0; j < 4; ++j) {
        float v = accl[n][j]; int idx = n * 16 + g * 4 + j;
        if (v > m1) { m2 = m1; i2 = i1; m1 = v; i1 = idx; }
        else if (v > m2) { m2 = v; i2 = idx; }
      }
    #pragma unroll
    for (int d = 16; d <= 32; d <<= 1) {   // merge across g-groups (same row)
      float om1 = __shfl_xor(m1, d); int oi1 = __shfl_xor(i1, d);
      float om2 = __shfl_xor(m2, d); int oi2 = __shfl_xor(i2, d);
      bool take = (om1 > m1) || (om1 == m1 && oi1 < i1);
      if (take) {
        float nm2; int ni2;
        if (m1 > om2 || (m1 == om2 && i1 < oi2)) { nm2 = m1; ni2 = i1; }
        else { nm2 = om2; ni2 = oi2; }
        m1 = om1; i1 = oi1; m2 = nm2; i2 = ni2;
      } else {
        if (om1 > m2 || (om1 == m2 && oi1 < i2)) { m2 = om1; i2 = oi1; }
      }
    }
    float a1 = __builtin_amdgcn_rcpf(
        1.0f + __builtin_amdgcn_exp2f((m2 - m1) * (1.44269504f / 0.7f)));
    float a2 = 1.0f - a1;
    const float* v1 = mvw + i1 * 128 + g * 32;
    const float* v2 = mvw + i2 * 128 + g * 32;
    #pragma unroll
    for (int c = 0; c < 4; ++c) {
      float4 A0 = *(const float4*)(v1 + c * 8), A1 = *(const float4*)(v1 + c * 8 + 4);
      float4 B0 = *(const float4*)(v2 + c * 8), B1 = *(const float4*)(v2 + c * 8 + 4);
      float4 r0 = {a1*A0.x + a2*B0.x, a1*A0.y + a2*B0.y, a1*A0.z + a2*B0.z, a1*A0.w + a2*B0.w};
      float4 r1 = {a1*A1.x + a2*B1.x, a1*A1.y + a2*B1.y, a1*A1.z + a2*B1.z, a1*A1.w + a2*B1.w};
      *(u16x8*)(fz + wr * 264 + 128 + g * 32 + c * 8) = cvt8(r0, r1);
    }
  }
  BARRIER_LGKM;                      // mem visible

  // =========== GEMM3: h = gelu(fused@w3+b3) [64x384], K=256, BK=32, no barriers ===========
  f32x4 acc3[4][6];
  #pragma unroll
  for (int m = 0; m < 4; ++m)
    #pragma unroll
    for (int n = 0; n < 6; ++n) acc3[m][n] = (f32x4){0.f, 0.f, 0.f, 0.f};
  for (int kt = 0; kt < 8; ++kt) {
    WAIT_VMN(0);                     // my strip(kt) landed
    u16x8 a3f[4], b3f[6];
    #pragma unroll
    for (int m = 0; m < 4; ++m)
      a3f[m] = *(const u16x8*)(fz + (m * 16 + l15) * 264 + kt * 32 + g * 8);
    #pragma unroll
    for (int n = 0; n < 6; ++n)
      b3f[n] = *(const u16x8*)(w3t + (wrow + n * 16 + l15) * 32 + sw8);
    WAIT_LGKM0;
    if (kt < 7) {
      const u16* s3 = w3s + (kt + 1) * 12288 + wstrip + lane * 8;
      #pragma unroll
      for (int i = 0; i < 6; ++i) gload16(s3 + i * 512, w3t + wstrip + i * 512);
    }
    #pragma unroll
    for (int m = 0; m < 4; ++m)
      #pragma unroll
      for (int n = 0; n < 6; ++n) acc3[m][n] = mfma16(b3f[n], a3f[m], acc3[m][n]);
  }

  // epilogue: per-row dot with w4; lane holds 4 consecutive cols -> 2-step shuffle reduce
  #pragma unroll
  for (int m = 0; m < 4; ++m) {
    float s = 0.f;
    #pragma unroll
    for (int n = 0; n < 6; ++n) {
      int col = wrow + n * 16 + g * 4;
      float4 bv = *(const float4*)(b3s + col);
      float4 wv = *(const float4*)(w4s + col);
      f32x4 a = acc3[m][n];
      s += gelu_fast(a[0] + bv.x) * wv.x + gelu_fast(a[1] + bv.y) * wv.y +
           gelu_fast(a[2] + bv.z) * wv.z + gelu_fast(a[3] + bv.w) * wv.w;
    }
    s += __shfl_xor(s, 16);
    s += __shfl_xor(s, 32);
    if (lane < 16) rowpart[(m * 16 + l15) * 4 + wid] = s;
  }
  BARRIER_LGKM;
  if (tid < BM) {
    const float4* rp = (const float4*)(rowpart + tid * 4);
    float4 p0 = rp[0];
    float lg = b4[0] + p0.x + p0.y + p0.z + p0.w;
    out[row0 + tid] = __builtin_amdgcn_rcpf(1.0f + __builtin_amdgcn_exp2f(-lg * 1.44269504f));
  }
}

// ---------------- launch ----------------
extern "C" void kernel_launch(void* const* d_in, const int* in_sizes, int n_in,
                              void* d_out, int out_size, void* d_ws, size_t ws_size,
                              hipStream_t stream) {
  const float* x  = (const float*)d_in[0];
  const float* w1 = (const float*)d_in[1];
  const float* b1 = (const float*)d_in[2];
  const float* w2 = (const float*)d_in[3];
  const float* b2 = (const float*)d_in[4];
  const float* mk = (const float*)d_in[5];
  const float* mv = (const float*)d_in[6];
  const float* w3 = (const float*)d_in[7];
  const float* b3 = (const float*)d_in[8];
  const float* w4 = (const float*)d_in[9];
  const float* b4 = (const float*)d_in[10];

  u16* w1s = (u16*)d_ws;            // 393216 u16 (32 swizzled [384][32] tiles)
  u16* w2s = w1s + 393216;          // 49152 (12 [128][32] tiles)
  u16* w3s = w1s + 442368;          // 98304 (8 [384][32] tiles)

  prep_kernel<<<2112, 256, 0, stream>>>(w1, w2, w3, w1s, w2s, w3s);

  (void)hipFuncSetAttribute(reinterpret_cast<const void*>(fused_kernel),
                            hipFuncAttributeMaxDynamicSharedMemorySize, SMEM_BYTES);
  fused_kernel<<<NBLK, BDIM, SMEM_BYTES, stream>>>(x, w1s, b1, w2s, b2, mk, mv, w3s,
                                                   b3, w4, b4, (float*)d_out);
}